// Round 11
// baseline (86.860 us; speedup 1.0000x reference)
//
#include <hip/hip_runtime.h>

#define SEQ 128
#define DM 32

// log2(e) * 2^23 : natural-exponent slope -> float-exponent-bit units
#define K_LOG2E_2P23 12102203.161561485f
// Schraudolph bias: (127 - 0.04384) * 2^23, minimax-balanced rel error (+/- ~3%)
#define SCHRAUDOLPH_C 1064985472.0f
#define INV_SQRT_D 0.17677669529663687f  // 1/sqrt(32)

// ---------------------------------------------------------------------------
// DPP wave reductions (VALU pipe; keeps the LDS unit free).
// Classic gfx9 chain: row_shr 1/2/4/8 then row_bcast15/31; lane 63 holds the
// full 64-lane result, broadcast to all lanes via readlane (SGPR).
// ---------------------------------------------------------------------------
template <int ctrl, bool zero>
__device__ __forceinline__ float dppf(float v) {
    return __int_as_float(__builtin_amdgcn_update_dpp(
        zero ? 0 : __float_as_int(v), __float_as_int(v), ctrl, 0xf, 0xf, zero));
}

__device__ __forceinline__ float wred_max(float v) {
    v = fmaxf(v, dppf<0x111, false>(v));
    v = fmaxf(v, dppf<0x112, false>(v));
    v = fmaxf(v, dppf<0x114, false>(v));
    v = fmaxf(v, dppf<0x118, false>(v));
    v = fmaxf(v, dppf<0x142, false>(v));
    v = fmaxf(v, dppf<0x143, false>(v));
    return __int_as_float(__builtin_amdgcn_readlane(__float_as_int(v), 63));
}

__device__ __forceinline__ float wred_min(float v) {
    v = fminf(v, dppf<0x111, false>(v));
    v = fminf(v, dppf<0x112, false>(v));
    v = fminf(v, dppf<0x114, false>(v));
    v = fminf(v, dppf<0x118, false>(v));
    v = fminf(v, dppf<0x142, false>(v));
    v = fminf(v, dppf<0x143, false>(v));
    return __int_as_float(__builtin_amdgcn_readlane(__float_as_int(v), 63));
}

// inclusive chain; lane 63 ends with the full 64-lane sum
__device__ __forceinline__ float wred_sum_lane63(float v) {
    v += dppf<0x111, true>(v);
    v += dppf<0x112, true>(v);
    v += dppf<0x114, true>(v);
    v += dppf<0x118, true>(v);
    v += dppf<0x142, true>(v);
    v += dppf<0x143, true>(v);
    return v;
}

// ---------------------------------------------------------------------------
// Kernel 0 (1 block, 64 thr): fold weights to 4 scalars. Algebra (R0):
// tokens are affine in the scalar x[b,s] -> the whole attention collapses to
//   out[b] = alpha * mean_q m(t_q) + beta,
//   m(t) = sum_k x_k e^{t x_k} / sum_k e^{t x_k},  t_q = a*x_q + c.
// K-bias cancels in softmax. A,C stored pre-scaled into exp-bit units.
// ---------------------------------------------------------------------------
__global__ void precompute_consts(const float* __restrict__ Wt,
                                  const float* __restrict__ bt,
                                  const float* __restrict__ Wq,
                                  const float* __restrict__ bq,
                                  const float* __restrict__ Wk,
                                  const float* __restrict__ bk,
                                  const float* __restrict__ Wv,
                                  const float* __restrict__ bv,
                                  const float* __restrict__ Wo,
                                  const float* __restrict__ bo,
                                  float* __restrict__ consts) {
    int e = threadIdx.x;  // 0..63
    float qw = 0.f, qb = 0.f, kw = 0.f, vw = 0.f, vb = 0.f;
    float wo = 0.f;
    if (e < DM) {
        for (int d = 0; d < DM; ++d) {
            float wt = Wt[d];
            float bb = bt[d];
            qw = fmaf(wt, Wq[d * DM + e], qw);
            qb = fmaf(bb, Wq[d * DM + e], qb);
            kw = fmaf(wt, Wk[d * DM + e], kw);
            vw = fmaf(wt, Wv[d * DM + e], vw);
            vb = fmaf(bb, Wv[d * DM + e], vb);
        }
        qb += bq[e];
        vb += bv[e];
        wo = Wo[e];  // Wo is (32,1) -> flat index e
    }
    float pa  = qw * kw;   // -> a * sqrt(D)
    float pc  = qb * kw;   // -> c * sqrt(D)
    float pal = vw * wo;   // -> alpha
    float pbe = vb * wo;   // -> beta - bo
    for (int off = 32; off > 0; off >>= 1) {
        pa  += __shfl_down(pa, off);
        pc  += __shfl_down(pc, off);
        pal += __shfl_down(pal, off);
        pbe += __shfl_down(pbe, off);
    }
    if (e == 0) {
        consts[0] = pa * (INV_SQRT_D * K_LOG2E_2P23);  // A (exp-bit units)
        consts[1] = pc * (INV_SQRT_D * K_LOG2E_2P23);  // C (exp-bit units)
        consts[2] = pal;                               // alpha
        consts[3] = pbe + bo[0];                       // beta
    }
}

// ---------------------------------------------------------------------------
// Dual-row table loop: each lane sums a QUARTER (32 k's) of TWO rows at its
// t-point. 4 independent accumulator chains (S0,U0,S1,U1) -> double the ILP
// of the single-row loop; both rows' ds_reads issue back-to-back. Reads
// rotated by 2*(lane&3) so the quad's 4 float4 addresses are bank-disjoint
// (m136). Schraudolph fast-exp: e = bitcast(int(Tp*x + Mp)); CLAMP guards
// int-underflow for rare high-dynamic-range rows (wave-uniform branch).
// ---------------------------------------------------------------------------
template <bool CLAMP>
__device__ __forceinline__ void table_loop_dual(const float4* __restrict__ base0,
                                                const float4* __restrict__ base1,
                                                int rot,
                                                float Tp0, float Mp0,
                                                float Tp1, float Mp1,
                                                float& S0, float& U0,
                                                float& S1, float& U1) {
#pragma unroll
    for (int i = 0; i < 8; ++i) {
        const int idx = (rot + i) & 7;
        const float4 xv0 = base0[idx];  // ds_read_b128
        const float4 xv1 = base1[idx];  // ds_read_b128
#pragma unroll
        for (int j = 0; j < 4; ++j) {
            const float a = (j == 0) ? xv0.x : (j == 1) ? xv0.y : (j == 2) ? xv0.z : xv0.w;
            const float b = (j == 0) ? xv1.x : (j == 1) ? xv1.y : (j == 2) ? xv1.z : xv1.w;
            float v0 = fmaf(Tp0, a, Mp0);
            float v1 = fmaf(Tp1, b, Mp1);
            if (CLAMP) {
                v0 = fmaxf(v0, 0.0f);
                v1 = fmaxf(v1, 0.0f);
            }
            const float e0 = __int_as_float((int)v0);
            const float e1 = __int_as_float((int)v1);
            S0 += e0; U0 = fmaf(e0, a, U0);
            S1 += e1; U1 = fmaf(e1, b, U1);
        }
    }
}

// ---------------------------------------------------------------------------
// Main kernel: 1024-thread blocks (16 waves), 2 rows per wave -> grid 512
// (was 4096 x 256-thr): 8x fewer workgroup dispatches, half the waves, and
// per-wave fixed costs (load-latency window, DPP chains, tail) amortized
// over 2 rows with 4 independent accumulator chains. No cross-wave LDS
// sharing -> no __syncthreads. m(t) via 16-point table + Catmull-Rom
// (error anchor: exact/61/29/13-cell all bit-identical absmax 0.03125).
// ---------------------------------------------------------------------------
#define WAVES_PER_BLOCK 16
#define ROWS_PER_WAVE 2
#define NPTS 16

__global__ __launch_bounds__(1024, 8) void attn_rowmean_kernel(
        const float* __restrict__ x,
        const float* __restrict__ consts,
        float* __restrict__ out, int B) {
    __shared__ float sx[WAVES_PER_BLOCK][ROWS_PER_WAVE][SEQ];
    __shared__ float tab[WAVES_PER_BLOCK][ROWS_PER_WAVE][NPTS];

    const int wave = threadIdx.x >> 6;
    const int lane = threadIdx.x & 63;
    int b0 = (blockIdx.x * WAVES_PER_BLOCK + wave) * ROWS_PER_WAVE;
    int b1 = b0 + 1;
    if (b0 >= B) b0 = B - 1;  // tail dup; idempotent writes
    if (b1 >= B) b1 = B - 1;

    const float A     = consts[0];
    const float C     = consts[1];
    const float alpha = consts[2];
    const float beta  = consts[3];

    // ---- both rows' loads issue in one latency window ----
    const float* xr0 = x + (size_t)b0 * SEQ;
    const float* xr1 = x + (size_t)b1 * SEQ;
    const float x00 = xr0[lane];
    const float x01 = xr0[lane + 64];
    const float x10 = xr1[lane];
    const float x11 = xr1[lane + 64];
    sx[wave][0][lane]      = x00;
    sx[wave][0][lane + 64] = x01;
    sx[wave][1][lane]      = x10;
    sx[wave][1][lane + 64] = x11;

    // per-row max/min via DPP chains (VALU pipe)
    const float mx0 = wred_max(fmaxf(x00, x01));
    const float mn0 = wred_min(fminf(x00, x01));
    const float mx1 = wred_max(fmaxf(x10, x11));
    const float mn1 = wred_min(fminf(x10, x11));

    // t-ranges (exp-bit units)
    const float Ta0 = fmaf(A, mn0, C), Tb0 = fmaf(A, mx0, C);
    const float Ta1 = fmaf(A, mn1, C), Tb1 = fmaf(A, mx1, C);
    const float Tlo0 = fminf(Ta0, Tb0), Thi0 = fmaxf(Ta0, Tb0);
    const float Tlo1 = fminf(Ta1, Tb1), Thi1 = fmaxf(Ta1, Tb1);
    const float span0 = Thi0 - Tlo0, span1 = Thi1 - Tlo1;
    const float h0 = span0 * (1.0f / 13.0f), h1 = span1 * (1.0f / 13.0f);
    const float invh0 = (span0 > 1e-6f) ? (13.0f / span0) : 0.0f;
    const float invh1 = (span1 > 1e-6f) ? (13.0f / span1) : 0.0f;

    // lane quad -> table point p (ghosts at p=0,15); c4 = k-quarter
    const int p  = lane >> 2;
    const int c4 = lane & 3;
    const float Tp0 = fmaf((float)(p - 1), h0, Tlo0);
    const float Tp1 = fmaf((float)(p - 1), h1, Tlo1);
    const float Mp0 = SCHRAUDOLPH_C - fmaxf(Tp0 * mx0, Tp0 * mn0);
    const float Mp1 = SCHRAUDOLPH_C - fmaxf(Tp1 * mx1, Tp1 * mn1);

    float S0 = 0.f, U0 = 0.f, S1 = 0.f, U1 = 0.f;
    const float4* base0 = (const float4*)sx[wave][0] + (c4 << 3);
    const float4* base1 = (const float4*)sx[wave][1] + (c4 << 3);
    const int rot = c4 << 1;

    // wave-uniform overflow-risk check (both rows must be safe for fast path)
    const float risk0 = fmaxf(fabsf(Tlo0 - h0), fabsf(Thi0 + h0)) * (mx0 - mn0);
    const float risk1 = fmaxf(fabsf(Tlo1 - h1), fabsf(Thi1 + h1)) * (mx1 - mn1);
    if (fmaxf(risk0, risk1) < 1.0e9f) {
        table_loop_dual<false>(base0, base1, rot, Tp0, Mp0, Tp1, Mp1, S0, U0, S1, U1);
    } else {
        table_loop_dual<true>(base0, base1, rot, Tp0, Mp0, Tp1, Mp1, S0, U0, S1, U1);
    }

    // combine the four k-quarters within the lane quad
    S0 += __shfl_xor(S0, 1); U0 += __shfl_xor(U0, 1);
    S1 += __shfl_xor(S1, 1); U1 += __shfl_xor(U1, 1);
    S0 += __shfl_xor(S0, 2); U0 += __shfl_xor(U0, 2);
    S1 += __shfl_xor(S1, 2); U1 += __shfl_xor(U1, 2);

    // all 4 lanes of the quad write the same value to the same slot
    tab[wave][0][p] = U0 * __builtin_amdgcn_rcpf(S0);
    tab[wave][1][p] = U1 * __builtin_amdgcn_rcpf(S1);

    // ---- Catmull-Rom interpolation: 2 q's per lane per row ----
    float msum0 = 0.f, msum1 = 0.f;
#pragma unroll
    for (int r = 0; r < 2; ++r) {
        const float xa = r ? x01 : x00;   // row0 q values
        const float xb = r ? x11 : x10;   // row1 q values
#pragma unroll
        for (int row = 0; row < 2; ++row) {
            const float t    = fmaf(A, row ? xb : xa, C);
            const float Tlo  = row ? Tlo1 : Tlo0;
            const float invh = row ? invh1 : invh0;
            float u = (t - Tlo) * invh;
            u = fminf(fmaxf(u, 0.0f), 13.0f);
            int c = (int)u;
            c = (c > 12) ? 12 : c;
            const float f = u - (float)c;
            const float* tb = &tab[wave][row][c];
            const float p0 = tb[0], p1 = tb[1], p2 = tb[2], p3 = tb[3];
            const float d1 = p2 - p0;
            const float c2 = 2.0f * p0 - 5.0f * p1 + 4.0f * p2 - p3;
            const float c3 = 3.0f * (p1 - p2) + (p3 - p0);
            const float val = fmaf(0.5f * f, fmaf(f, fmaf(f, c3, c2), d1), p1);
            if (row) msum1 += val; else msum0 += val;
        }
    }

    // per-row mean over 128 q via DPP sum; lane 63 stores
    msum0 = wred_sum_lane63(msum0);
    msum1 = wred_sum_lane63(msum1);
    if (lane == 63) {
        out[b0] = fmaf(alpha, msum0 * (1.0f / 128.0f), beta);
        out[b1] = fmaf(alpha, msum1 * (1.0f / 128.0f), beta);
    }
}

extern "C" void kernel_launch(void* const* d_in, const int* in_sizes, int n_in,
                              void* d_out, int out_size, void* d_ws, size_t ws_size,
                              hipStream_t stream) {
    const float* x  = (const float*)d_in[0];
    const float* Wt = (const float*)d_in[1];
    const float* bt = (const float*)d_in[2];
    const float* Wq = (const float*)d_in[3];
    const float* bq = (const float*)d_in[4];
    const float* Wk = (const float*)d_in[5];
    const float* bk = (const float*)d_in[6];  // cancels in softmax; unused
    const float* Wv = (const float*)d_in[7];
    const float* bv = (const float*)d_in[8];
    const float* Wo = (const float*)d_in[9];
    const float* bo = (const float*)d_in[10];
    float* out = (float*)d_out;
    float* consts = (float*)d_ws;  // 4 floats

    const int B = in_sizes[0] / SEQ;

    precompute_consts<<<1, 64, 0, stream>>>(Wt, bt, Wq, bq, Wk, bk, Wv, bv,
                                            Wo, bo, consts);

    const int rows_per_block = WAVES_PER_BLOCK * ROWS_PER_WAVE;
    const int grid = (B + rows_per_block - 1) / rows_per_block;
    attn_rowmean_kernel<<<grid, 1024, 0, stream>>>(x, consts, out, B);
}

// Round 13
// 84.318 us; speedup vs baseline: 1.0301x; 1.0301x over previous
//
#include <hip/hip_runtime.h>

#define SEQ 128
#define DM 32

// log2(e) * 2^23 : natural-exponent slope -> float-exponent-bit units
#define K_LOG2E_2P23 12102203.161561485f
// Schraudolph bias: (127 - 0.04384) * 2^23, minimax-balanced rel error (+/- ~3%)
#define SCHRAUDOLPH_C 1064985472.0f
#define INV_SQRT_D 0.17677669529663687f  // 1/sqrt(32)

// ---------------------------------------------------------------------------
// DPP wave reductions (VALU pipe; keeps the LDS unit free).
// Classic gfx9 chain: row_shr 1/2/4/8 then row_bcast15/31; lane 63 holds the
// full 64-lane result, broadcast via readlane (SGPR).
// ---------------------------------------------------------------------------
template <int ctrl, bool zero>
__device__ __forceinline__ float dppf(float v) {
    return __int_as_float(__builtin_amdgcn_update_dpp(
        zero ? 0 : __float_as_int(v), __float_as_int(v), ctrl, 0xf, 0xf, zero));
}

__device__ __forceinline__ float wred_max(float v) {
    v = fmaxf(v, dppf<0x111, false>(v));
    v = fmaxf(v, dppf<0x112, false>(v));
    v = fmaxf(v, dppf<0x114, false>(v));
    v = fmaxf(v, dppf<0x118, false>(v));
    v = fmaxf(v, dppf<0x142, false>(v));
    v = fmaxf(v, dppf<0x143, false>(v));
    return __int_as_float(__builtin_amdgcn_readlane(__float_as_int(v), 63));
}

__device__ __forceinline__ float wred_min(float v) {
    v = fminf(v, dppf<0x111, false>(v));
    v = fminf(v, dppf<0x112, false>(v));
    v = fminf(v, dppf<0x114, false>(v));
    v = fminf(v, dppf<0x118, false>(v));
    v = fminf(v, dppf<0x142, false>(v));
    v = fminf(v, dppf<0x143, false>(v));
    return __int_as_float(__builtin_amdgcn_readlane(__float_as_int(v), 63));
}

// inclusive chain; lane 63 ends with the full 64-lane sum
__device__ __forceinline__ float wred_sum_lane63(float v) {
    v += dppf<0x111, true>(v);
    v += dppf<0x112, true>(v);
    v += dppf<0x114, true>(v);
    v += dppf<0x118, true>(v);
    v += dppf<0x142, true>(v);
    v += dppf<0x143, true>(v);
    return v;
}

// ---------------------------------------------------------------------------
// Kernel 0 (1 block, 64 thr): fold weights to 4 scalars. Algebra (R0):
// tokens are affine in the scalar x[b,s] -> the whole attention collapses to
//   out[b] = alpha * mean_q m(t_q) + beta,
//   m(t) = sum_k x_k e^{t x_k} / sum_k e^{t x_k},  t_q = a*x_q + c.
// K-bias cancels in softmax. A,C stored pre-scaled into exp-bit units.
// ---------------------------------------------------------------------------
__global__ void precompute_consts(const float* __restrict__ Wt,
                                  const float* __restrict__ bt,
                                  const float* __restrict__ Wq,
                                  const float* __restrict__ bq,
                                  const float* __restrict__ Wk,
                                  const float* __restrict__ bk,
                                  const float* __restrict__ Wv,
                                  const float* __restrict__ bv,
                                  const float* __restrict__ Wo,
                                  const float* __restrict__ bo,
                                  float* __restrict__ consts) {
    int e = threadIdx.x;  // 0..63
    float qw = 0.f, qb = 0.f, kw = 0.f, vw = 0.f, vb = 0.f;
    float wo = 0.f;
    if (e < DM) {
        for (int d = 0; d < DM; ++d) {
            float wt = Wt[d];
            float bb = bt[d];
            qw = fmaf(wt, Wq[d * DM + e], qw);
            qb = fmaf(bb, Wq[d * DM + e], qb);
            kw = fmaf(wt, Wk[d * DM + e], kw);
            vw = fmaf(wt, Wv[d * DM + e], vw);
            vb = fmaf(bb, Wv[d * DM + e], vb);
        }
        qb += bq[e];
        vb += bv[e];
        wo = Wo[e];  // Wo is (32,1) -> flat index e
    }
    float pa  = qw * kw;   // -> a * sqrt(D)
    float pc  = qb * kw;   // -> c * sqrt(D)
    float pal = vw * wo;   // -> alpha
    float pbe = vb * wo;   // -> beta - bo
    for (int off = 32; off > 0; off >>= 1) {
        pa  += __shfl_down(pa, off);
        pc  += __shfl_down(pc, off);
        pal += __shfl_down(pal, off);
        pbe += __shfl_down(pbe, off);
    }
    if (e == 0) {
        consts[0] = pa * (INV_SQRT_D * K_LOG2E_2P23);  // A (exp-bit units)
        consts[1] = pc * (INV_SQRT_D * K_LOG2E_2P23);  // C (exp-bit units)
        consts[2] = pal;                               // alpha
        consts[3] = pbe + bo[0];                       // beta
    }
}

// ---------------------------------------------------------------------------
// Table-point partial series over a QUARTER of the row (32 k's): S = sum e_k,
// U = sum e_k x_k at this lane's t-point. Lane quads share a t-point and
// split the k-range; reads rotated by 2*(lane&3) so the quad's 4 distinct
// float4 addresses are bank-disjoint (conflict-free; m136).
// Schraudolph fast-exp: e = bitcast(int(Tp*x + Mp)); CLAMP guards
// int-underflow for rare high-dynamic-range rows (wave-uniform branch).
// ---------------------------------------------------------------------------
template <bool CLAMP>
__device__ __forceinline__ void table_loop_quarter(const float4* __restrict__ base,
                                                   int rot, float Tp, float Mp,
                                                   float& S, float& U) {
#pragma unroll
    for (int i = 0; i < 8; ++i) {
        const float4 xv = base[(rot + i) & 7];  // ds_read_b128, skewed
#pragma unroll
        for (int j = 0; j < 4; ++j) {
            const float xk = (j == 0) ? xv.x : (j == 1) ? xv.y : (j == 2) ? xv.z : xv.w;
            float v = fmaf(Tp, xk, Mp);
            if (CLAMP) v = fmaxf(v, 0.0f);
            const float e = __int_as_float((int)v);
            S += e;
            U = fmaf(e, xk, U);
        }
    }
}

// ---------------------------------------------------------------------------
// Main kernel: one wave per row (confirmed optimum frame; 2-row and 1024-thr
// variants regressed). All 128 q share the scalar function m(t); build a
// 16-point table (lane quad -> point p = lane>>2: T_p = Tlo+(p-1)h, points
// 0/15 are ghosts, 13 interior cells), then Catmull-Rom cubic interpolate
// each q's m(t_q) from the LDS table.
// ACCURACY CLIFF (R12 post-mortem): t-span is |a|*(mx-mn) ~ 5-9 natural
// units (a has unit variance after the folds), so 13 cells -> h ~ 0.5 (CR
// error under the 3% Schraudolph floor, validated bit-identical absmax);
// 5 cells -> h ~ 1.5 FAILS (absmax 0.756). Do not shrink below 16 points.
// x row loaded as one float2/lane (q-assignment is a permutation; q-mean
// and min/max are order-invariant).
// ---------------------------------------------------------------------------
#define WAVES_PER_BLOCK 4
#define NPTS 16

__global__ __launch_bounds__(256) void attn_rowmean_kernel(
        const float* __restrict__ x,
        const float* __restrict__ consts,
        float* __restrict__ out, int B) {
    __shared__ float sx[WAVES_PER_BLOCK][SEQ];
    __shared__ float tab[WAVES_PER_BLOCK][NPTS];

    const int wave = threadIdx.x >> 6;
    const int lane = threadIdx.x & 63;
    int b = blockIdx.x * WAVES_PER_BLOCK + wave;
    if (b >= B) b = B - 1;  // tail dup; idempotent writes

    const float A     = consts[0];
    const float C     = consts[1];
    const float alpha = consts[2];
    const float beta  = consts[3];

    const float* xr = x + (size_t)b * SEQ;
    const float2 xv2 = ((const float2*)xr)[lane];  // one global_load_dwordx2
    const float x0 = xv2.x;
    const float x1 = xv2.y;
    ((float2*)sx[wave])[lane] = xv2;               // one ds_write_b64

    // row max/min via DPP chains (VALU pipe)
    const float mx = wred_max(fmaxf(x0, x1));
    const float mn = wred_min(fminf(x0, x1));

    // t-range over this row's q values (exp-bit units)
    const float Ta = fmaf(A, mn, C);
    const float Tb = fmaf(A, mx, C);
    const float Tlo = fminf(Ta, Tb);
    const float Thi = fmaxf(Ta, Tb);
    const float spanT = Thi - Tlo;
    const float h = spanT * (1.0f / 13.0f);
    const float invh = (spanT > 1e-6f) ? (13.0f / spanT) : 0.0f;

    // lane quad -> table point p: T_p = Tlo + (p-1)*h (p=0,15 = ghosts)
    const int p   = lane >> 2;
    const int c4  = lane & 3;   // which quarter of the row this lane sums
    const float Tp = fmaf((float)(p - 1), h, Tlo);
    const float Mp = SCHRAUDOLPH_C - fmaxf(Tp * mx, Tp * mn);

    float S = 0.f, U = 0.f;
    const float4* base = (const float4*)sx[wave] + (c4 << 3);
    const int rot = c4 << 1;

    // wave-uniform overflow-risk check over the extreme (ghost) table points
    const float maxTpt = fmaxf(fabsf(Tlo - h), fabsf(Thi + h));
    if (maxTpt * (mx - mn) < 1.0e9f) {
        table_loop_quarter<false>(base, rot, Tp, Mp, S, U);
    } else {
        table_loop_quarter<true>(base, rot, Tp, Mp, S, U);
    }

    // combine the four k-quarters within the lane quad
    S += __shfl_xor(S, 1);
    U += __shfl_xor(U, 1);
    S += __shfl_xor(S, 2);
    U += __shfl_xor(U, 2);

    // all 4 lanes of the quad write the same value to the same slot
    tab[wave][p] = U * __builtin_amdgcn_rcpf(S);

    // ---- Catmull-Rom interpolation for this lane's two q values ----
    const float t0 = fmaf(A, x0, C);
    const float t1 = fmaf(A, x1, C);
    float msum = 0.f;
#pragma unroll
    for (int r = 0; r < 2; ++r) {
        const float t = r ? t1 : t0;
        float u = (t - Tlo) * invh;           // in [0, 13] by construction
        u = fminf(fmaxf(u, 0.0f), 13.0f);     // safety clamp
        int c = (int)u;                        // cell index
        c = (c > 12) ? 12 : c;
        const float f = u - (float)c;          // in [0, 1]
        // CR nodes: tab[c..c+3] (cell spans points c+1 .. c+2)
        const float* tb = &tab[wave][c];
        const float p0 = tb[0], p1 = tb[1], p2 = tb[2], p3 = tb[3];
        const float d1 = p2 - p0;
        const float c2 = 2.0f * p0 - 5.0f * p1 + 4.0f * p2 - p3;
        const float c3 = 3.0f * (p1 - p2) + (p3 - p0);
        msum += fmaf(0.5f * f, fmaf(f, fmaf(f, c3, c2), d1), p1);
    }

    // mean over the row's 128 q via DPP sum; lane 63 holds the total
    msum = wred_sum_lane63(msum);
    if (lane == 63)
        out[b] = fmaf(alpha, msum * (1.0f / 128.0f), beta);
}

extern "C" void kernel_launch(void* const* d_in, const int* in_sizes, int n_in,
                              void* d_out, int out_size, void* d_ws, size_t ws_size,
                              hipStream_t stream) {
    const float* x  = (const float*)d_in[0];
    const float* Wt = (const float*)d_in[1];
    const float* bt = (const float*)d_in[2];
    const float* Wq = (const float*)d_in[3];
    const float* bq = (const float*)d_in[4];
    const float* Wk = (const float*)d_in[5];
    const float* bk = (const float*)d_in[6];  // cancels in softmax; unused
    const float* Wv = (const float*)d_in[7];
    const float* bv = (const float*)d_in[8];
    const float* Wo = (const float*)d_in[9];
    const float* bo = (const float*)d_in[10];
    float* out = (float*)d_out;
    float* consts = (float*)d_ws;  // 4 floats

    const int B = in_sizes[0] / SEQ;

    precompute_consts<<<1, 64, 0, stream>>>(Wt, bt, Wq, bq, Wk, bk, Wv, bv,
                                            Wo, bo, consts);

    const int grid = (B + WAVES_PER_BLOCK - 1) / WAVES_PER_BLOCK;
    attn_rowmean_kernel<<<grid, 256, 0, stream>>>(x, consts, out, B);
}